// Round 3
// baseline (338.954 us; speedup 1.0000x reference)
//
#include <hip/hip_runtime.h>

// Conv bank of 17 fixed filters + ReLU over (128,1,32768) fp32.
// out[b,j,t] = relu( sum_k W[j,k] * x_pad[b, t+k-47] ), pad (47,48).
//
// v4: one OUTPUT STREAM per block (write spatial locality).
//   Evidence: v1/v2/v3 (three different compute structures, store spreading,
//   raw barriers, occupancy changes) all ~298us -> duration is set by the
//   write address pattern. Old decomposition: each block wrote 17 streams
//   strided 128KB -> ~26k concurrent 4KB write regions (DRAM page thrash,
//   ~2.5 TB/s effective vs fill's 6.4 TB/s sequential).
//   New: block = (b, j, half-row). 16 sequential chunks of 1024 -> ONE
//   contiguous 64KB write stream per block (~2k concurrent streams).
//   - XCD-aware remap: xcd = g&7 owns 16 b-rows; the 34 blocks sharing a row
//     land on one XCD's L2 -> x HBM reads stay ~17MB despite 17x re-staging.
//   - T14 prefetch: chunk c+1 global loads issued before chunk c compute,
//     regs->LDS write after the read fence barrier.
//   - Compute paths (scan/P-diff for alternating, Z-factorized / direct
//     bumps) inherited bitwise from the passing v3 kernel.

#define S_LEN    32768
#define NTHREADS 256
#define TILE     1024
#define NCHK     16        // chunks per half-row
#define PITCH    284       // P plane pitch (need >= 278)
#define NSCAN    139       // 8-elem scan chunks covering P reads (max idx 1104)

typedef float fvec4 __attribute__((ext_vector_type(4)));

// ---------------- weights (compile-time, exact vs numpy fp32) -------------
template<int Qv>
__device__ __forceinline__ float bw(int i) {           // half-bump B, len 2Q
    constexpr float inv = 1.0f / (float)Qv;
    const float t = (i < Qv) ? (float)(i + 1) * inv : (float)(2 * Qv - i) * inv;
    return t * t;
}
template<int Qv>
__device__ __forceinline__ float third_w(int j) {      // full bump, len 6Q
    constexpr float inv = 1.0f / (float)Qv;
    const int seg = j / Qv;
    const int i = j - seg * Qv;
    const float t = ((seg & 1) == 0) ? (float)(i + 1) * inv : (float)(Qv - i) * inv;
    const float v = t * t;
    return (seg == 2 || seg == 3) ? 2.0f * v : -v;
}

// ---------------- staging: x[ts-48 .. ts+1072) -> xsl[0..1120) ------------
struct StageRegs { float4 a, b; };

__device__ __forceinline__ float4 guarded_ld(const float4* __restrict__ g4, int w) {
    if ((unsigned)w < (unsigned)(S_LEN / 4)) return g4[w];
    return make_float4(0.f, 0.f, 0.f, 0.f);
}
__device__ __forceinline__ StageRegs stage_load(const float4* __restrict__ g4,
                                                int ts, int tid) {
    const int wb = (ts >> 2) - 12;      // 48 = 12 words of left halo
    StageRegs r;
    r.a = guarded_ld(g4, wb + tid);
    r.b = (tid < 24) ? guarded_ld(g4, wb + 256 + tid)
                     : make_float4(0.f, 0.f, 0.f, 0.f);
    return r;
}
__device__ __forceinline__ void stage_write(float* __restrict__ xsl,
                                            const StageRegs& r, int tid) {
    float4* s4 = reinterpret_cast<float4*>(xsl);
    s4[tid] = r.a;
    if (tid < 24) s4[256 + tid] = r.b;
}

// ---------------- output ----------------
__device__ __forceinline__ void store_relu(float* __restrict__ p, float4 v) {
    fvec4 s;
    s.x = fmaxf(v.x, 0.f); s.y = fmaxf(v.y, 0.f);
    s.z = fmaxf(v.z, 0.f); s.w = fmaxf(v.w, 0.f);
    __builtin_nontemporal_store(s, reinterpret_cast<fvec4*>(p));
}

// ---------------- bump: Z = B*x staged in LDS (q = 4, 8, 16) --------------
template<int Qv>
__device__ __forceinline__ void zcalc(const float* __restrict__ xsl,
                                      float* __restrict__ Zf, int bi) {
    constexpr int OFF  = 49 - 3 * Qv;   // 37, 25, 1
    constexpr int A0Q  = OFF >> 2;
    constexpr int SH   = OFF & 3;
    constexpr int SPAN = 2 * Qv;
    constexpr int NW   = (SH + SPAN + 3 + 3) >> 2;
    const float4* __restrict__ xs4 =
        reinterpret_cast<const float4*>(xsl) + bi + A0Q;
    float a0 = 0.f, a1 = 0.f, a2 = 0.f, a3 = 0.f;
#pragma unroll
    for (int wi = 0; wi < NW; ++wi) {
        const float4 xw = xs4[wi];                 // lane-stride 16B: conflict-free
#pragma unroll
        for (int e = 0; e < 4; ++e) {
            const int u = 4 * wi + e - SH;         // compile-time after unroll
            const float xv = (e == 0) ? xw.x : (e == 1) ? xw.y
                           : (e == 2) ? xw.z : xw.w;
            if (u >= 0 && u < SPAN)     a0 = fmaf(bw<Qv>(u),     xv, a0);
            if (u >= 1 && u < SPAN + 1) a1 = fmaf(bw<Qv>(u - 1), xv, a1);
            if (u >= 2 && u < SPAN + 2) a2 = fmaf(bw<Qv>(u - 2), xv, a2);
            if (u >= 3 && u < SPAN + 3) a3 = fmaf(bw<Qv>(u - 3), xv, a3);
        }
    }
    reinterpret_cast<float4*>(Zf)[bi] = make_float4(a0, a1, a2, a3);
}

template<int Qv>
__device__ __forceinline__ float4 bump_out(const float* __restrict__ Zf, int tid) {
    const float4* __restrict__ Z4 = reinterpret_cast<const float4*>(Zf);
    const float4 za = Z4[tid];
    const float4 zb = Z4[tid + (Qv >> 1)];
    const float4 zc = Z4[tid + Qv];
    float4 y;
    y.x = fmaf(2.f, zb.x, -(za.x + zc.x));
    y.y = fmaf(2.f, zb.y, -(za.y + zc.y));
    y.z = fmaf(2.f, zb.z, -(za.z + zc.z));
    y.w = fmaf(2.f, zb.w, -(za.w + zc.w));
    return y;
}

// ---------------- bump direct (q = 1, 2) ----------------------------------
template<int Qv>
__device__ __forceinline__ float4 bump_direct(const float* __restrict__ xsl, int tid) {
    constexpr int SPAN = 6 * Qv;
    constexpr int C    = (SPAN - 1) / 2;
    constexpr int OFF  = 48 - C;        // 46 (q=1), 43 (q=2)
    constexpr int A0   = OFF >> 2;
    constexpr int SH   = OFF & 3;
    constexpr int NW   = (SH + SPAN + 3 + 3) >> 2;
    const float4* __restrict__ xs4 =
        reinterpret_cast<const float4*>(xsl) + tid + A0;
    float a0 = 0.f, a1 = 0.f, a2 = 0.f, a3 = 0.f;
#pragma unroll
    for (int wi = 0; wi < NW; ++wi) {
        const float4 xw = xs4[wi];
#pragma unroll
        for (int e = 0; e < 4; ++e) {
            const int u = 4 * wi + e - SH;
            const float xv = (e == 0) ? xw.x : (e == 1) ? xw.y
                           : (e == 2) ? xw.z : xw.w;
            if (u >= 0 && u < SPAN)     a0 = fmaf(third_w<Qv>(u),     xv, a0);
            if (u >= 1 && u < SPAN + 1) a1 = fmaf(third_w<Qv>(u - 1), xv, a1);
            if (u >= 2 && u < SPAN + 2) a2 = fmaf(third_w<Qv>(u - 2), xv, a2);
            if (u >= 3 && u < SPAN + 3) a3 = fmaf(third_w<Qv>(u - 3), xv, a3);
        }
    }
    return make_float4(a0, a1, a2, a3);
}

// ---------------- alternating filter via P differences --------------------
template<int K>
__device__ __forceinline__ float4 alt_acc(const float* __restrict__ Psp, int tid) {
    constexpr int H = (K - 1) / 2;
    float v[4];
#pragma unroll
    for (int r = 0; r < 4; ++r) {
        const int dn  = 48 - H + r;
        const int dn2 = dn + K;
        const float pa = Psp[(dn  & 3) * PITCH + tid + (dn  >> 2)];
        const float pb = Psp[(dn2 & 3) * PITCH + tid + (dn2 >> 2)];
        const float dd = pb - pa;
        v[r] = ((r + H) & 1) ? dd : -dd;
    }
    return make_float4(v[0], v[1], v[2], v[3]);
}

// ================= per-filter chunk loops =================================
template<int K, bool NEG>
__device__ __forceinline__ void run_alt(const float4* __restrict__ g4,
                                        float* __restrict__ smem,
                                        float* __restrict__ outp,
                                        int tbase, int tid) {
    float* xsl  = smem;                 // 1120
    float* Psp  = smem + 1120;          // 1136
    float* wtot = smem + 1120 + 1136;   // 2
    const float4* xs4 = reinterpret_cast<const float4*>(xsl);

    StageRegs nxt = stage_load(g4, tbase, tid);
    stage_write(xsl, nxt, tid);
    for (int c = 0; c < NCHK; ++c) {
        __syncthreads();                             // xsl(c) visible
        if (c + 1 < NCHK) nxt = stage_load(g4, tbase + (c + 1) * TILE, tid);
        float4 xa, xb; float csum = 0.f;
        if (tid < NSCAN) {
            xa = xs4[2 * tid]; xb = xs4[2 * tid + 1];
            csum = (xa.x - xa.y) + (xa.z - xa.w)
                 + (xb.x - xb.y) + (xb.z - xb.w);
        }
        float incl = csum;
#pragma unroll
        for (int off = 1; off < 64; off <<= 1) {
            const float v = __shfl_up(incl, off, 64);
            if ((tid & 63) >= off) incl += v;
        }
        if ((tid & 63) == 63 && tid < 128) wtot[tid >> 6] = incl;
        __syncthreads();                             // xsl reads done; wtot ready
        if (c + 1 < NCHK) stage_write(xsl, nxt, tid);
        if (tid < NSCAN) {
            float offs = (tid >= 64) ? wtot[0] : 0.f;
            if (tid >= 128) offs += wtot[1];
            float run = offs + (incl - csum);        // P[8*tid]
            float* Pb = Psp + 2 * tid;               // lane-stride 8B: free
            Pb[0 * PITCH + 0] = run; run += xa.x;
            Pb[1 * PITCH + 0] = run; run -= xa.y;
            Pb[2 * PITCH + 0] = run; run += xa.z;
            Pb[3 * PITCH + 0] = run; run -= xa.w;
            Pb[0 * PITCH + 1] = run; run += xb.x;
            Pb[1 * PITCH + 1] = run; run -= xb.y;
            Pb[2 * PITCH + 1] = run; run += xb.z;
            Pb[3 * PITCH + 1] = run;
        }
        __syncthreads();                             // P ready
        float4 v = alt_acc<K>(Psp, tid);
        if (NEG) { v.x = -v.x; v.y = -v.y; v.z = -v.z; v.w = -v.w; }
        store_relu(outp + tbase + c * TILE, v);
    }
}

template<int Qv>
__device__ __forceinline__ void run_bumpZ(const float4* __restrict__ g4,
                                          float* __restrict__ smem,
                                          float* __restrict__ outp,
                                          int tbase, int tid) {
    float* xsl = smem;
    float* Zb  = smem + 1120;           // 256 + Qv float4 words
    StageRegs nxt = stage_load(g4, tbase, tid);
    stage_write(xsl, nxt, tid);
    for (int c = 0; c < NCHK; ++c) {
        __syncthreads();                             // xsl(c) visible; prev Z reads done
        if (c + 1 < NCHK) nxt = stage_load(g4, tbase + (c + 1) * TILE, tid);
        zcalc<Qv>(xsl, Zb, tid);
        if (tid >= NTHREADS - Qv)                    // halo Z words
            zcalc<Qv>(xsl, Zb, 256 + (tid - (NTHREADS - Qv)));
        __syncthreads();                             // Z ready; xsl reads done
        if (c + 1 < NCHK) stage_write(xsl, nxt, tid);
        store_relu(outp + tbase + c * TILE, bump_out<Qv>(Zb, tid));
    }
}

template<int Qv>
__device__ __forceinline__ void run_bumpD(const float4* __restrict__ g4,
                                          float* __restrict__ smem,
                                          float* __restrict__ outp,
                                          int tbase, int tid) {
    float* xsl = smem;
    StageRegs nxt = stage_load(g4, tbase, tid);
    stage_write(xsl, nxt, tid);
    for (int c = 0; c < NCHK; ++c) {
        __syncthreads();                             // xsl(c) visible
        if (c + 1 < NCHK) nxt = stage_load(g4, tbase + (c + 1) * TILE, tid);
        const float4 y = bump_direct<Qv>(xsl, tid);
        __syncthreads();                             // xsl reads done
        if (c + 1 < NCHK) stage_write(xsl, nxt, tid);
        store_relu(outp + tbase + c * TILE, y);
    }
}

// ================= kernel =================================================
__global__ __launch_bounds__(NTHREADS, 8)
void conv_bank_kernel(const float* __restrict__ x, float* __restrict__ out) {
    __shared__ __align__(16) float smem[1120 + 1136 + 2];

    const int tid = threadIdx.x;
    const int g   = blockIdx.x;
    // XCD-aware remap (performance heuristic): xcd g&7 owns 16 b-rows, so the
    // 34 blocks sharing a row stay on one XCD's L2.
    const int xcd = g & 7;
    const int i   = g >> 3;             // 0..543
    const int bi  = i / 34;             // 0..15
    const int r   = i - bi * 34;        // 0..33
    const int b   = xcd * 16 + bi;      // 0..127
    const int j   = r >> 1;             // 0..16
    const int tbase = (r & 1) * (S_LEN / 2);

    const float4* g4 = reinterpret_cast<const float4*>(x + (size_t)b * S_LEN);
    float* outp = out + ((size_t)b * 17 + j) * S_LEN + 4 * tid;

    switch (j) {
    case 0:  run_alt<2,  false>(g4, smem, outp, tbase, tid); break;
    case 1:  run_alt<4,  false>(g4, smem, outp, tbase, tid); break;
    case 2:  run_alt<8,  false>(g4, smem, outp, tbase, tid); break;
    case 3:  run_alt<16, false>(g4, smem, outp, tbase, tid); break;
    case 4:  run_alt<32, false>(g4, smem, outp, tbase, tid); break;
    case 5:  run_alt<64, false>(g4, smem, outp, tbase, tid); break;
    case 6:  run_alt<2,  true >(g4, smem, outp, tbase, tid); break;
    case 7:  run_alt<4,  true >(g4, smem, outp, tbase, tid); break;
    case 8:  run_alt<8,  true >(g4, smem, outp, tbase, tid); break;
    case 9:  run_alt<16, true >(g4, smem, outp, tbase, tid); break;
    case 10: run_alt<32, true >(g4, smem, outp, tbase, tid); break;
    case 11: run_alt<64, true >(g4, smem, outp, tbase, tid); break;
    case 12: run_bumpD<1 >(g4, smem, outp, tbase, tid); break;
    case 13: run_bumpD<2 >(g4, smem, outp, tbase, tid); break;
    case 14: run_bumpZ<4 >(g4, smem, outp, tbase, tid); break;
    case 15: run_bumpZ<8 >(g4, smem, outp, tbase, tid); break;
    case 16: run_bumpZ<16>(g4, smem, outp, tbase, tid); break;
    }
}

extern "C" void kernel_launch(void* const* d_in, const int* in_sizes, int n_in,
                              void* d_out, int out_size, void* d_ws, size_t ws_size,
                              hipStream_t stream) {
    const float* x = (const float*)d_in[0];
    float* out = (float*)d_out;
    (void)in_sizes; (void)n_in; (void)d_ws; (void)ws_size; (void)out_size;
    dim3 grid(128 * 17 * 2, 1, 1);      // (b, j, half) flattened, XCD-remapped
    conv_bank_kernel<<<grid, NTHREADS, 0, stream>>>(x, out);
}